// Round 7
// baseline (122.990 us; speedup 1.0000x reference)
//
#include <hip/hip_runtime.h>
#include <math.h>
#include <stdint.h>

#define KCODES 512
#define DIM 64
#define NROWS (64 * 4096)     // B*S = 262144
#define BLOCK 256             // 4 waves
#define ROWS_PER_WAVE 32
#define BM (BLOCK / 64 * ROWS_PER_WAVE)   // 128 rows per block
#define NBLK (NROWS / BM)                 // 2048 blocks

typedef __bf16 bf16x8 __attribute__((ext_vector_type(8)));
typedef float f32x4 __attribute__((ext_vector_type(4)));

// ---------------------------------------------------------------------------
// Kernel A (prep, runs once): per code k
//   en1[k] = 1.0 + ||e_k||^2                      (exact fp32)
//   ebf[k*64 + j] = bf16(-2 * e_k[j])             (row-major, UNswizzled --
//   B-fragments are read from L2, not LDS, so no bank-conflict concern)
// ---------------------------------------------------------------------------
__global__ void vq_prep_kernel(const float* __restrict__ emb,
                               float* __restrict__ en1,
                               __bf16* __restrict__ ebf) {
    int k = blockIdx.x * blockDim.x + threadIdx.x;
    if (k >= KCODES) return;
    const float4* e4 = reinterpret_cast<const float4*>(emb + k * DIM);
    float s0 = 0.f, s1 = 0.f, s2 = 0.f, s3 = 0.f;
#pragma unroll
    for (int j = 0; j < 8; ++j) {          // 8 chunks of 8 elems
        float4 v0 = e4[j * 2];
        float4 v1 = e4[j * 2 + 1];
        s0 = fmaf(v0.x, v0.x, s0); s1 = fmaf(v0.y, v0.y, s1);
        s2 = fmaf(v0.z, v0.z, s2); s3 = fmaf(v0.w, v0.w, s3);
        s0 = fmaf(v1.x, v1.x, s0); s1 = fmaf(v1.y, v1.y, s1);
        s2 = fmaf(v1.z, v1.z, s2); s3 = fmaf(v1.w, v1.w, s3);
        bf16x8 p;
        p[0] = (__bf16)(-2.f * v0.x); p[1] = (__bf16)(-2.f * v0.y);
        p[2] = (__bf16)(-2.f * v0.z); p[3] = (__bf16)(-2.f * v0.w);
        p[4] = (__bf16)(-2.f * v1.x); p[5] = (__bf16)(-2.f * v1.y);
        p[6] = (__bf16)(-2.f * v1.z); p[7] = (__bf16)(-2.f * v1.w);
        *reinterpret_cast<bf16x8*>(&ebf[k * DIM + j * 8]) = p;
    }
    en1[k] = 1.0f + (s0 + s1) + (s2 + s3);
}

// ---------------------------------------------------------------------------
// Kernel B: MFMA scoring + packed-key argmin + per-wave gather + loss.
//   score_k(+1) = en1[k] + x . (-2 e_k)   via acc-init = en1, bf16 MFMA
//   key = (as_uint(score) & ~511) | k ; umin; tie -> smaller k.
// NO LDS STAGING: ebf (64 KB) is L2-resident on every XCD; B-fragments and
// en1 load straight from L2. Blocks are tiny (4 waves, ~no LDS) and fully
// independent -> blocks retire/launch continuously, HBM traffic streams
// instead of bursting in lockstep phases. (Common-mistake #7 fix.)
// ---------------------------------------------------------------------------
__launch_bounds__(BLOCK, 6)
__global__ void vq_mfma_kernel(const float* __restrict__ lat,
                               const float* __restrict__ emb,
                               const float* __restrict__ en1,
                               const __bf16* __restrict__ ebf,
                               float* __restrict__ outq,
                               float* __restrict__ partials) {
    __shared__ float wsum_lds[BLOCK / 64];

    const int t = threadIdx.x;
    const int lane = t & 63, wid = t >> 6;
    const int l15 = lane & 15, lq = lane >> 4;
    const size_t waverow = (size_t)blockIdx.x * BM + (size_t)wid * ROWS_PER_WAVE;

    // ---- A fragments: global -> reg, convert to bf16.
    bf16x8 afrag[2][2];
#pragma unroll
    for (int mf = 0; mf < 2; ++mf) {
#pragma unroll
        for (int ks = 0; ks < 2; ++ks) {
            const float* xp =
                lat + (waverow + mf * 16 + l15) * DIM + ks * 32 + lq * 8;
            float4 v0 = reinterpret_cast<const float4*>(xp)[0];
            float4 v1 = reinterpret_cast<const float4*>(xp)[1];
            bf16x8 a;
            a[0] = (__bf16)v0.x; a[1] = (__bf16)v0.y;
            a[2] = (__bf16)v0.z; a[3] = (__bf16)v0.w;
            a[4] = (__bf16)v1.x; a[5] = (__bf16)v1.y;
            a[6] = (__bf16)v1.z; a[7] = (__bf16)v1.w;
            afrag[mf][ks] = a;
        }
    }

    uint32_t best[2][4];
#pragma unroll
    for (int mf = 0; mf < 2; ++mf)
#pragma unroll
        for (int r = 0; r < 4; ++r) best[mf][r] = 0xFFFFFFFFu;

    // ---- scoring: 32 groups of 16 codes; B-frags + en straight from L2.
    //   B-frag mapping: lane holds E[n = l&15][k = 32*ks + 8*lq + b]
#pragma unroll 4
    for (int nf = 0; nf < 32; ++nf) {
        const int n = nf * 16 + l15;
        const __bf16* bp = ebf + n * DIM + lq * 8;
        bf16x8 b0 = *reinterpret_cast<const bf16x8*>(bp);        // ks=0
        bf16x8 b1 = *reinterpret_cast<const bf16x8*>(bp + 32);   // ks=1
        float en = en1[n];
        f32x4 acc0 = {en, en, en, en};
        f32x4 acc1 = {en, en, en, en};
        acc0 = __builtin_amdgcn_mfma_f32_16x16x32_bf16(afrag[0][0], b0, acc0, 0, 0, 0);
        acc0 = __builtin_amdgcn_mfma_f32_16x16x32_bf16(afrag[0][1], b1, acc0, 0, 0, 0);
        acc1 = __builtin_amdgcn_mfma_f32_16x16x32_bf16(afrag[1][0], b0, acc1, 0, 0, 0);
        acc1 = __builtin_amdgcn_mfma_f32_16x16x32_bf16(afrag[1][1], b1, acc1, 0, 0, 0);
        const uint32_t nn = (uint32_t)n;
#pragma unroll
        for (int r = 0; r < 4; ++r) {
            uint32_t k0 = (__float_as_uint(acc0[r]) & 0xFFFFFE00u) | nn;
            uint32_t k1 = (__float_as_uint(acc1[r]) & 0xFFFFFE00u) | nn;
            best[0][r] = min(best[0][r], k0);
            best[1][r] = min(best[1][r], k1);
        }
    }

    // ---- cross-lane umin butterfly: afterwards ALL 16 col-lanes hold the
    // min for rows rw = mf*16 + lq*4 + r (tie -> smaller idx, free).
#pragma unroll
    for (int off = 1; off < 16; off <<= 1) {
#pragma unroll
        for (int mf = 0; mf < 2; ++mf)
#pragma unroll
            for (int r = 0; r < 4; ++r) {
                uint32_t o = (uint32_t)__shfl_xor((int)best[mf][r], off, 64);
                best[mf][r] = min(best[mf][r], o);
            }
    }

    // ---- per-wave gather: lane (lq,l15) writes float4-chunk l15 of row
    // waverow + mf*16 + lq*4 + r. lat tile re-read is L2-hot.
    float lsum = 0.f;
    const float4* emb4 = reinterpret_cast<const float4*>(emb);
    const float4* lat4 = reinterpret_cast<const float4*>(lat);
    float4* out4 = reinterpret_cast<float4*>(outq);
#pragma unroll
    for (int mf = 0; mf < 2; ++mf) {
#pragma unroll
        for (int r = 0; r < 4; ++r) {
            const uint32_t k = best[mf][r] & 511u;
            const size_t grow = waverow + mf * 16 + lq * 4 + r;
            float4 e4 = emb4[k * 16 + l15];
            float4 x4 = lat4[grow * 16 + l15];
            out4[grow * 16 + l15] = e4;
            float d0 = e4.x - x4.x, d1 = e4.y - x4.y;
            float d2 = e4.z - x4.z, d3 = e4.w - x4.w;
            lsum = fmaf(d0, d0, lsum);
            lsum = fmaf(d1, d1, lsum);
            lsum = fmaf(d2, d2, lsum);
            lsum = fmaf(d3, d3, lsum);
        }
    }

    // ---- deterministic block reduce (only barrier in the kernel)
#pragma unroll
    for (int off = 32; off > 0; off >>= 1)
        lsum += __shfl_down(lsum, off, 64);
    if (lane == 0) wsum_lds[wid] = lsum;
    __syncthreads();
    if (t == 0) {
        float s = 0.f;
#pragma unroll
        for (int w = 0; w < BLOCK / 64; ++w) s += wsum_lds[w];
        partials[blockIdx.x] = s;
    }
}

// ---------------------------------------------------------------------------
// Kernel C: reduce partials -> vq_loss = 1.25 * mean((q-x)^2)
// ---------------------------------------------------------------------------
__global__ void vq_loss_kernel(const float* __restrict__ partials,
                               float* __restrict__ loss) {
    float s = 0.f;
    for (int i = threadIdx.x; i < NBLK; i += 256) s += partials[i];
#pragma unroll
    for (int off = 32; off > 0; off >>= 1)
        s += __shfl_down(s, off, 64);
    __shared__ float wsum[4];
    const int lane = threadIdx.x & 63;
    const int wid = threadIdx.x >> 6;
    if (lane == 0) wsum[wid] = s;
    __syncthreads();
    if (threadIdx.x == 0) {
        float tsum = 0.f;
#pragma unroll
        for (int w = 0; w < 4; ++w) tsum += wsum[w];
        loss[0] = 1.25f * (tsum / (float)((size_t)NROWS * DIM));
    }
}

// ---------------------------------------------------------------------------
extern "C" void kernel_launch(void* const* d_in, const int* in_sizes, int n_in,
                              void* d_out, int out_size, void* d_ws, size_t ws_size,
                              hipStream_t stream) {
    const float* lat = (const float*)d_in[0];   // [B,S,D] fp32
    const float* emb = (const float*)d_in[1];   // [K,D]   fp32
    float* outq = (float*)d_out;                              // output 0
    float* loss = (float*)d_out + (size_t)NROWS * DIM;        // output 1

    // ws layout (bytes): [0,2048)        en1 f32[512]
    //                    [2048, 67584)   ebf bf16[512*64] (row-major, x -2)
    //                    [67584, 75776)  partials f32[2048]
    float* en1 = (float*)d_ws;
    __bf16* ebf = (__bf16*)((char*)d_ws + 2048);
    float* partials = (float*)((char*)d_ws + 67584);

    vq_prep_kernel<<<2, 256, 0, stream>>>(emb, en1, ebf);
    vq_mfma_kernel<<<NBLK, BLOCK, 0, stream>>>(lat, emb, en1, ebf, outq, partials);
    vq_loss_kernel<<<1, 256, 0, stream>>>(partials, loss);
}

// Round 8
// 40.905 us; speedup vs baseline: 3.0068x; 3.0068x over previous
//
#include <hip/hip_runtime.h>
#include <math.h>
#include <stdint.h>

#define KCODES 512
#define DIM 64
#define NROWS (64 * 4096)     // B*S = 262144
#define BLOCK 512             // 8 waves
#define GROUP_ROWS 32         // rows per wave per pipeline group (2 mf tiles)
#define ROWS_PER_WAVE 64      // 2 groups, pipelined
#define BM ((BLOCK / 64) * ROWS_PER_WAVE)   // 512 rows per block
#define NBLK (NROWS / BM)                   // 512 blocks = 2 per CU

typedef __bf16 bf16x8 __attribute__((ext_vector_type(8)));
typedef float f32x4 __attribute__((ext_vector_type(4)));

typedef __attribute__((address_space(3))) uint32_t* lds_ptr_t;
typedef const __attribute__((address_space(1))) uint32_t* glb_ptr_t;

// ---------------------------------------------------------------------------
// Kernel A (prep, runs once): per code k
//   en1[k] = 1.0 + ||e_k||^2 (exact fp32)
//   ebf[k*64 + (j ^ (k&7))*8 ..] = bf16(-2 * e_k[j*8..])  (pre-swizzled, -2x)
// ---------------------------------------------------------------------------
__global__ void vq_prep_kernel(const float* __restrict__ emb,
                               float* __restrict__ en1,
                               __bf16* __restrict__ ebf) {
    int k = blockIdx.x * blockDim.x + threadIdx.x;
    if (k >= KCODES) return;
    const float4* e4 = reinterpret_cast<const float4*>(emb + k * DIM);
    float s0 = 0.f, s1 = 0.f, s2 = 0.f, s3 = 0.f;
#pragma unroll
    for (int j = 0; j < 8; ++j) {
        float4 v0 = e4[j * 2];
        float4 v1 = e4[j * 2 + 1];
        s0 = fmaf(v0.x, v0.x, s0); s1 = fmaf(v0.y, v0.y, s1);
        s2 = fmaf(v0.z, v0.z, s2); s3 = fmaf(v0.w, v0.w, s3);
        s0 = fmaf(v1.x, v1.x, s0); s1 = fmaf(v1.y, v1.y, s1);
        s2 = fmaf(v1.z, v1.z, s2); s3 = fmaf(v1.w, v1.w, s3);
        bf16x8 p;
        p[0] = (__bf16)(-2.f * v0.x); p[1] = (__bf16)(-2.f * v0.y);
        p[2] = (__bf16)(-2.f * v0.z); p[3] = (__bf16)(-2.f * v0.w);
        p[4] = (__bf16)(-2.f * v1.x); p[5] = (__bf16)(-2.f * v1.y);
        p[6] = (__bf16)(-2.f * v1.z); p[7] = (__bf16)(-2.f * v1.w);
        *reinterpret_cast<bf16x8*>(&ebf[k * DIM + (j ^ (k & 7)) * 8]) = p;
    }
    en1[k] = 1.0f + (s0 + s1) + (s2 + s3);
}

// ---------------------------------------------------------------------------
// Kernel B: pipelined MFMA scoring + packed-key argmin + gather + loss.
//   score_k(+1) = en1[k] + x . (-2 e_k)   (acc-init = en1, bf16 MFMA)
//   key = (as_uint(score+1) & ~511) | k ; umin; tie -> smaller k.
//   loss row-sum = (score+1) - 1 + ||x||^2  -> no lat re-read in gather.
// Pipeline per wave: load A(g0) | stage E | cvt A(g0), ISSUE A(g1) loads |
//   score g0 (A(g1) read flies under it) | gather+write g0 (stores drain
//   under next phase) | cvt A(g1) | score g1 | gather+write g1.
// ---------------------------------------------------------------------------
__launch_bounds__(BLOCK, 4)
__global__ void vq_mfma_kernel(const float* __restrict__ lat,
                               const float* __restrict__ emb,
                               const float* __restrict__ en1,
                               const __bf16* __restrict__ ebf,
                               float* __restrict__ outq,
                               float* __restrict__ partials) {
    __shared__ __align__(16) __bf16 e_lds[KCODES * DIM];  // 64 KB, swizzled
    __shared__ float en_lds[KCODES];                      // 2 KB
    __shared__ float wsum_lds[BLOCK / 64];

    const int t = threadIdx.x;
    const int lane = t & 63, wid = t >> 6;
    const int l15 = lane & 15, lq = lane >> 4;
    const int swz = l15 & 7;
    const uint32_t waverow = (uint32_t)blockIdx.x * BM + (uint32_t)wid * ROWS_PER_WAVE;

    // ---- stage E: bf16 ws -> LDS, 16B/lane, linear dest (src pre-swizzled).
#pragma unroll
    for (int i = 0; i < 8; ++i) {
        int c = t + i * BLOCK;
        __builtin_amdgcn_global_load_lds(
            (glb_ptr_t)(const void*)(ebf + c * 8),
            (lds_ptr_t)(void*)(&e_lds[c * 8]), 16, 0, 0);
    }

    float4 araw[2][2][2];   // [mf][ks][half] raw fp32 A for one group
    auto load_a = [&](int g) {
#pragma unroll
        for (int mf = 0; mf < 2; ++mf)
#pragma unroll
            for (int ks = 0; ks < 2; ++ks) {
                const float* xp = lat +
                    (waverow + (uint32_t)g * GROUP_ROWS + mf * 16 + l15) * DIM +
                    ks * 32 + lq * 8;
                araw[mf][ks][0] = reinterpret_cast<const float4*>(xp)[0];
                araw[mf][ks][1] = reinterpret_cast<const float4*>(xp)[1];
            }
    };

    load_a(0);
    en_lds[t] = en1[t];   // BLOCK == KCODES
    __syncthreads();      // E + en ready (only whole-block barrier)

    float xsq = 0.f, lsum = 0.f;
    bf16x8 afrag[2][2];
    uint32_t best[2][4];

    // convert raw A -> bf16 frags; accumulate exact ||x||^2 from fp32
    auto cvt_a = [&]() {
#pragma unroll
        for (int mf = 0; mf < 2; ++mf)
#pragma unroll
            for (int ks = 0; ks < 2; ++ks) {
                float4 v0 = araw[mf][ks][0], v1 = araw[mf][ks][1];
                xsq = fmaf(v0.x, v0.x, xsq); xsq = fmaf(v0.y, v0.y, xsq);
                xsq = fmaf(v0.z, v0.z, xsq); xsq = fmaf(v0.w, v0.w, xsq);
                xsq = fmaf(v1.x, v1.x, xsq); xsq = fmaf(v1.y, v1.y, xsq);
                xsq = fmaf(v1.z, v1.z, xsq); xsq = fmaf(v1.w, v1.w, xsq);
                bf16x8 a;
                a[0] = (__bf16)v0.x; a[1] = (__bf16)v0.y;
                a[2] = (__bf16)v0.z; a[3] = (__bf16)v0.w;
                a[4] = (__bf16)v1.x; a[5] = (__bf16)v1.y;
                a[6] = (__bf16)v1.z; a[7] = (__bf16)v1.w;
                afrag[mf][ks] = a;
            }
    };

    auto score = [&]() {
#pragma unroll
        for (int mf = 0; mf < 2; ++mf)
#pragma unroll
            for (int r = 0; r < 4; ++r) best[mf][r] = 0xFFFFFFFFu;
#pragma unroll 4
        for (int nf = 0; nf < 32; ++nf) {
            const int n = nf * 16 + l15;
            bf16x8 b0 = *reinterpret_cast<const bf16x8*>(
                &e_lds[n * DIM + (lq ^ swz) * 8]);
            bf16x8 b1 = *reinterpret_cast<const bf16x8*>(
                &e_lds[n * DIM + ((lq + 4) ^ swz) * 8]);
            float en = en_lds[n];
            f32x4 acc0 = {en, en, en, en};
            f32x4 acc1 = {en, en, en, en};
            acc0 = __builtin_amdgcn_mfma_f32_16x16x32_bf16(afrag[0][0], b0, acc0, 0, 0, 0);
            acc0 = __builtin_amdgcn_mfma_f32_16x16x32_bf16(afrag[0][1], b1, acc0, 0, 0, 0);
            acc1 = __builtin_amdgcn_mfma_f32_16x16x32_bf16(afrag[1][0], b0, acc1, 0, 0, 0);
            acc1 = __builtin_amdgcn_mfma_f32_16x16x32_bf16(afrag[1][1], b1, acc1, 0, 0, 0);
            const uint32_t nn = (uint32_t)n;
#pragma unroll
            for (int r = 0; r < 4; ++r) {
                uint32_t k0 = (__float_as_uint(acc0[r]) & 0xFFFFFE00u) | nn;
                uint32_t k1 = (__float_as_uint(acc1[r]) & 0xFFFFFE00u) | nn;
                best[0][r] = min(best[0][r], k0);
                best[1][r] = min(best[1][r], k1);
            }
        }
    };

    auto finish = [&](int g) {
        // butterfly umin over 16 col-lanes: all lanes end with row minima
#pragma unroll
        for (int off = 1; off < 16; off <<= 1) {
#pragma unroll
            for (int mf = 0; mf < 2; ++mf)
#pragma unroll
                for (int r = 0; r < 4; ++r) {
                    uint32_t o = (uint32_t)__shfl_xor((int)best[mf][r], off, 64);
                    best[mf][r] = min(best[mf][r], o);
                }
        }
        // loss from keys: row-sum (q-x)^2 = (score+1) - 1 + ||x||^2
        if (l15 == 0) {
#pragma unroll
            for (int mf = 0; mf < 2; ++mf)
#pragma unroll
                for (int r = 0; r < 4; ++r)
                    lsum += __uint_as_float(best[mf][r] & 0xFFFFFE00u) - 1.0f;
        }
        // gather chosen codes + write output (fire-and-forget stores)
        const float4* emb4 = reinterpret_cast<const float4*>(emb);
        float4* out4 = reinterpret_cast<float4*>(outq);
#pragma unroll
        for (int mf = 0; mf < 2; ++mf) {
#pragma unroll
            for (int r = 0; r < 4; ++r) {
                const uint32_t k = best[mf][r] & 511u;
                const uint32_t grow =
                    waverow + (uint32_t)g * GROUP_ROWS + mf * 16 + lq * 4 + r;
                float4 e4 = emb4[k * 16 + l15];
                out4[grow * 16 + l15] = e4;
            }
        }
    };

    // ---- pipelined main body
    cvt_a();        // waits A(g0); frees araw regs
    load_a(1);      // A(g1) HBM read flies under score(g0)
    score();
    finish(0);      // g0 stores drain under cvt/score of g1
    cvt_a();
    score();
    finish(1);

    lsum += xsq;

    // ---- deterministic block reduce
#pragma unroll
    for (int off = 32; off > 0; off >>= 1)
        lsum += __shfl_down(lsum, off, 64);
    if (lane == 0) wsum_lds[wid] = lsum;
    __syncthreads();
    if (t == 0) {
        float s = 0.f;
#pragma unroll
        for (int w = 0; w < BLOCK / 64; ++w) s += wsum_lds[w];
        partials[blockIdx.x] = s;
    }
}

// ---------------------------------------------------------------------------
// Kernel C: reduce partials -> vq_loss = 1.25 * mean((q-x)^2)
// ---------------------------------------------------------------------------
__global__ void vq_loss_kernel(const float* __restrict__ partials,
                               float* __restrict__ loss) {
    float s = 0.f;
    for (int i = threadIdx.x; i < NBLK; i += 256) s += partials[i];
#pragma unroll
    for (int off = 32; off > 0; off >>= 1)
        s += __shfl_down(s, off, 64);
    __shared__ float wsum[4];
    const int lane = threadIdx.x & 63;
    const int wid = threadIdx.x >> 6;
    if (lane == 0) wsum[wid] = s;
    __syncthreads();
    if (threadIdx.x == 0) {
        float tsum = 0.f;
#pragma unroll
        for (int w = 0; w < 4; ++w) tsum += wsum[w];
        loss[0] = 1.25f * (tsum / (float)((size_t)NROWS * DIM));
    }
}

// ---------------------------------------------------------------------------
extern "C" void kernel_launch(void* const* d_in, const int* in_sizes, int n_in,
                              void* d_out, int out_size, void* d_ws, size_t ws_size,
                              hipStream_t stream) {
    const float* lat = (const float*)d_in[0];   // [B,S,D] fp32
    const float* emb = (const float*)d_in[1];   // [K,D]   fp32
    float* outq = (float*)d_out;                              // output 0
    float* loss = (float*)d_out + (size_t)NROWS * DIM;        // output 1

    // ws layout (bytes): [0,2048)        en1 f32[512]
    //                    [2048, 67584)   ebf bf16[512*64] (pre-swizzled, x -2)
    //                    [67584, 69632)  partials f32[512]
    float* en1 = (float*)d_ws;
    __bf16* ebf = (__bf16*)((char*)d_ws + 2048);
    float* partials = (float*)((char*)d_ws + 67584);

    vq_prep_kernel<<<2, 256, 0, stream>>>(emb, en1, ebf);
    vq_mfma_kernel<<<NBLK, BLOCK, 0, stream>>>(lat, emb, en1, ebf, outq, partials);
    vq_loss_kernel<<<1, 256, 0, stream>>>(partials, loss);
}